// Round 3
// baseline (974.780 us; speedup 1.0000x reference)
//
#include <hip/hip_runtime.h>

typedef unsigned int uint;

// ---------------- bf16 pack/unpack helpers ----------------

__device__ __forceinline__ uint pack_bf2(float a, float b) {
    uint ua = __float_as_uint(a), ub = __float_as_uint(b);
    ua = (ua + 0x7FFFu + ((ua >> 16) & 1u)) >> 16;        // RNE to bf16
    ub = (ub + 0x7FFFu + ((ub >> 16) & 1u)) >> 16;
    return ua | (ub << 16);
}
__device__ __forceinline__ float bf_lo(uint u) { return __uint_as_float(u << 16); }
__device__ __forceinline__ float bf_hi(uint u) { return __uint_as_float(u & 0xFFFF0000u); }

// ---------------- CSR build (bucketed) ----------------

// 512-bucket histogram of dst>>8, LDS pre-aggregated
__global__ __launch_bounds__(256) void kb_hist(const int* __restrict__ dst,
                                               int* __restrict__ bhist, int E, int NB) {
    extern __shared__ int lh[];
    int tid = threadIdx.x;
    for (int i = tid; i < NB; i += 256) lh[i] = 0;
    __syncthreads();
    for (int e = blockIdx.x * 256 + tid; e < E; e += gridDim.x * 256)
        atomicAdd(&lh[dst[e] >> 8], 1);
    __syncthreads();
    for (int i = tid; i < NB; i += 256)
        if (lh[i]) atomicAdd(&bhist[i], lh[i]);
}

// exclusive scan of 512 bucket counts -> boff, bcur
__global__ void kb_scan(const int* __restrict__ bhist, int* __restrict__ boff,
                        int* __restrict__ bcur) {
    __shared__ int tmp[512];
    int tid = threadIdx.x;
    int v = bhist[tid];
    tmp[tid] = v;
    for (int d = 1; d < 512; d <<= 1) {
        __syncthreads();
        int t = (tid >= d) ? tmp[tid - d] : 0;
        __syncthreads();
        tmp[tid] += t;
    }
    int excl = tmp[tid] - v;
    boff[tid] = excl;
    bcur[tid] = excl;
}

// partition edges into buckets: packed[(cursor)] = (src<<8)|dst_local
__global__ void kb_part(const int* __restrict__ src, const int* __restrict__ dst,
                        int* __restrict__ bcur, uint* __restrict__ packed, int E) {
    int e = blockIdx.x * 256 + threadIdx.x;
    if (e < E) {
        int s = src[e], d = dst[e];
        int p = atomicAdd(&bcur[d >> 8], 1);
        packed[p] = ((uint)s << 8) | (uint)(d & 255);
    }
}

// per-bucket: exact per-node degrees, offsets, dinv, and final CSR fill
__global__ __launch_bounds__(256) void kb_build(const uint* __restrict__ packed,
                                                const int* __restrict__ boff,
                                                const int* __restrict__ bcur,
                                                int* __restrict__ degi,
                                                float* __restrict__ dinv,
                                                int* __restrict__ off,
                                                int* __restrict__ csr_s) {
    __shared__ int lh[256];
    __shared__ int lscan[256];
    __shared__ int lcur[256];
    int tid = threadIdx.x;
    int b = blockIdx.x;
    int base = boff[b];
    int cntE = bcur[b] - base;

    lh[tid] = 0;
    __syncthreads();
    for (int i = tid; i < cntE; i += 256)
        atomicAdd(&lh[packed[base + i] & 255u], 1);
    __syncthreads();
    int dg = lh[tid];
    lscan[tid] = dg;
    for (int d = 1; d < 256; d <<= 1) {
        __syncthreads();
        int t = (tid >= d) ? lscan[tid - d] : 0;
        __syncthreads();
        lscan[tid] += t;
    }
    int excl = lscan[tid] - dg;
    int node = (b << 8) + tid;
    degi[node] = dg;
    dinv[node] = rsqrtf((float)dg + 1.0f);
    off[node] = base + excl;
    lcur[tid] = excl;
    __syncthreads();
    for (int i = tid; i < cntE; i += 256) {
        uint u = packed[base + i];
        int d = (int)(u & 255u);
        int r = atomicAdd(&lcur[d], 1);
        csr_s[base + r] = (int)(u >> 8);
    }
}

// per-graph node counts
__global__ void k_cnt(const int* __restrict__ batch, float* __restrict__ cnt, int N) {
    int v = blockIdx.x * 256 + threadIdx.x;
    if (v < N) atomicAdd(&cnt[batch[v]], 1.0f);
}

// ---------------- y = x @ W1, output packed bf16 ----------------

__global__ __launch_bounds__(256) void k_gemm64_bf16(const float* __restrict__ A,
                                                     const float* __restrict__ W,
                                                     uint* __restrict__ ybf) {
    __shared__ float As[64][65];
    __shared__ float Ws[64][64];
    int tid = threadIdx.x;
    int r0 = blockIdx.x * 64;
    {
        int r = tid >> 2, cg = tid & 3;
        const float4* A4 = (const float4*)(A + (size_t)(r0 + r) * 64);
#pragma unroll
        for (int i = 0; i < 4; i++) {
            float4 a = A4[cg + 4 * i];
            int c = (cg + 4 * i) * 4;
            As[r][c + 0] = a.x; As[r][c + 1] = a.y; As[r][c + 2] = a.z; As[r][c + 3] = a.w;
        }
        const float4* W4 = (const float4*)W;
#pragma unroll
        for (int i = 0; i < 4; i++) {
            int idx = tid + 256 * i;
            float4 w = W4[idx];
            int k = idx >> 4, c = (idx & 15) * 4;
            *(float4*)&Ws[k][c] = w;
        }
    }
    __syncthreads();
    int ty = tid >> 4, tx = tid & 15;
    float acc[4][4] = {};
#pragma unroll 16
    for (int kk = 0; kk < 64; kk++) {
        float4 wv = *(const float4*)&Ws[kk][tx * 4];
        float a0 = As[ty * 4 + 0][kk];
        float a1 = As[ty * 4 + 1][kk];
        float a2 = As[ty * 4 + 2][kk];
        float a3 = As[ty * 4 + 3][kk];
        acc[0][0] += a0 * wv.x; acc[0][1] += a0 * wv.y; acc[0][2] += a0 * wv.z; acc[0][3] += a0 * wv.w;
        acc[1][0] += a1 * wv.x; acc[1][1] += a1 * wv.y; acc[1][2] += a1 * wv.z; acc[1][3] += a1 * wv.w;
        acc[2][0] += a2 * wv.x; acc[2][1] += a2 * wv.y; acc[2][2] += a2 * wv.z; acc[2][3] += a2 * wv.w;
        acc[3][0] += a3 * wv.x; acc[3][1] += a3 * wv.y; acc[3][2] += a3 * wv.z; acc[3][3] += a3 * wv.w;
    }
#pragma unroll
    for (int i = 0; i < 4; i++) {
        uint2 o;
        o.x = pack_bf2(acc[i][0], acc[i][1]);
        o.y = pack_bf2(acc[i][2], acc[i][3]);
        *(uint2*)&ybf[(size_t)(r0 + ty * 4 + i) * 32 + tx * 2] = o;
    }
}

// ---------------- pass 1: gather + relu-dot -> z ----------------
// 32 lanes per node (2 features each), 2 nodes per wave

__global__ __launch_bounds__(256) void k_gather(const uint* __restrict__ ybf,
                                                const int* __restrict__ csr_s,
                                                const int* __restrict__ off,
                                                const int* __restrict__ degi,
                                                const float* __restrict__ dinv,
                                                const float2* __restrict__ b1_2,
                                                const float2* __restrict__ vv_2,
                                                float* __restrict__ z) {
    int tid = threadIdx.x;
    int lane = tid & 31;
    int v = blockIdx.x * 8 + (tid >> 5);
    float dv = dinv[v];
    int base = off[v], ce = degi[v];
    uint uy = ybf[(size_t)v * 32 + lane];
    float w0 = dv * dv;
    float ax = w0 * bf_lo(uy);
    float ay = w0 * bf_hi(uy);
    for (int j = 0; j < ce; j++) {
        int s = csr_s[base + j];
        float w = dv * dinv[s];
        uint u = ybf[(size_t)s * 32 + lane];
        ax += w * bf_lo(u);
        ay += w * bf_hi(u);
    }
    float2 b = b1_2[lane];
    float2 vv = vv_2[lane];
    float p = fmaxf(ax + b.x, 0.f) * vv.x + fmaxf(ay + b.y, 0.f) * vv.y;
#pragma unroll
    for (int m = 1; m < 32; m <<= 1) p += __shfl_xor(p, m);
    if (lane == 0) z[v] = p;
}

// ---------------- pass 2: aggregate z, pool into out_g ----------------

__global__ __launch_bounds__(256) void k_pass2(const float* __restrict__ z,
                                               const int* __restrict__ csr_s,
                                               const int* __restrict__ off,
                                               const int* __restrict__ degi,
                                               const float* __restrict__ dinv,
                                               const int* __restrict__ batch,
                                               float* __restrict__ out_g) {
    int v = blockIdx.x * 256 + threadIdx.x;
    float dv = dinv[v];
    int base = off[v], ce = degi[v];
    float acc = dv * dv * z[v];
    for (int j = 0; j < ce; j++) {
        int s = csr_s[base + j];
        acc += dv * dinv[s] * z[s];
    }
    atomicAdd(&out_g[batch[v]], acc);
}

// ---------------- fold trailing affine layers ----------------

__global__ void k_precompute(const float* __restrict__ fc1_W, const float* __restrict__ fc1_b,
                             const float* __restrict__ fcf_W, const float* __restrict__ fcf_b,
                             const float* __restrict__ gcn_fc_W, const float* __restrict__ gcn_fc_b,
                             const float* __restrict__ conv2_W, const float* __restrict__ conv2_b,
                             const float* __restrict__ emb_W2, const float* __restrict__ emb_b2,
                             float* __restrict__ vv, float* __restrict__ uu, float* __restrict__ Cc) {
    __shared__ float t1s[128], t2s[128];
    int tid = threadIdx.x;
    if (tid < 128) {
        float s = 0;
        for (int j = 0; j < 64; j++) s += fc1_W[tid * 64 + j] * fcf_W[j];
        t1s[tid] = s;
    }
    __syncthreads();
    if (tid < 128) {
        float s = 0;
        for (int m = 0; m < 64; m++) s += gcn_fc_W[tid * 64 + m] * t1s[64 + m];
        t2s[tid] = s;
    }
    __syncthreads();
    if (tid < 64) {
        float s = 0;
        for (int p = 0; p < 128; p++) s += conv2_W[tid * 128 + p] * t2s[p];
        vv[tid] = s;
    }
    for (int j = tid; j < 1024; j += 256) {
        float s = 0;
        for (int k = 0; k < 64; k++) s += emb_W2[j * 64 + k] * t1s[k];
        uu[j] = s;
    }
    if (tid == 0) {
        float c = fcf_b[0];
        for (int j = 0; j < 64; j++)  c += fc1_b[j] * fcf_W[j];
        for (int k = 0; k < 64; k++)  c += emb_b2[k] * t1s[k];
        for (int p = 0; p < 128; p++) c += conv2_b[p] * t2s[p];
        for (int m = 0; m < 64; m++)  c += gcn_fc_b[m] * t1s[64 + m];
        Cc[0] = c;
    }
}

__global__ void k_ginit(const float* __restrict__ out_g, const float* __restrict__ cnt,
                        const float* __restrict__ Cc, float* __restrict__ out, int B) {
    int b = blockIdx.x * 256 + threadIdx.x;
    if (b < B) {
        float c = cnt[b]; c = c < 1.f ? 1.f : c;
        out[b] = out_g[b] / c + Cc[0];
    }
}

// ---------------- embedding GEMM + relu-dot epilogue ----------------

__global__ __launch_bounds__(256) void k_embgemm(const float* __restrict__ A,
                                                 const float* __restrict__ Bm,
                                                 const float* __restrict__ b1,
                                                 const float* __restrict__ uu,
                                                 float* __restrict__ out) {
    __shared__ float As[16][68];
    __shared__ float Bs[16][64];
    int tid = threadIdx.x;
    int r0 = blockIdx.x * 64, n0 = blockIdx.y * 64;
    int ty = tid >> 4, tx = tid & 15;
    float acc[4][4] = {};

    for (int k0 = 0; k0 < 768; k0 += 16) {
        {
            int r = tid >> 2, kg = tid & 3;
            float4 a = *(const float4*)&A[(size_t)(r0 + r) * 768 + k0 + kg * 4];
            As[kg * 4 + 0][r] = a.x; As[kg * 4 + 1][r] = a.y;
            As[kg * 4 + 2][r] = a.z; As[kg * 4 + 3][r] = a.w;
            float4 b = *(const float4*)&Bm[(size_t)(k0 + (tid >> 4)) * 1024 + n0 + (tid & 15) * 4];
            *(float4*)&Bs[tid >> 4][(tid & 15) * 4] = b;
        }
        __syncthreads();
#pragma unroll
        for (int kk = 0; kk < 16; kk++) {
            float4 av = *(const float4*)&As[kk][ty * 4];
            float4 bv = *(const float4*)&Bs[kk][tx * 4];
            acc[0][0] += av.x * bv.x; acc[0][1] += av.x * bv.y; acc[0][2] += av.x * bv.z; acc[0][3] += av.x * bv.w;
            acc[1][0] += av.y * bv.x; acc[1][1] += av.y * bv.y; acc[1][2] += av.y * bv.z; acc[1][3] += av.y * bv.w;
            acc[2][0] += av.z * bv.x; acc[2][1] += av.z * bv.y; acc[2][2] += av.z * bv.z; acc[2][3] += av.z * bv.w;
            acc[3][0] += av.w * bv.x; acc[3][1] += av.w * bv.y; acc[3][2] += av.w * bv.z; acc[3][3] += av.w * bv.w;
        }
        __syncthreads();
    }

#pragma unroll
    for (int i = 0; i < 4; i++) {
        float p = 0;
#pragma unroll
        for (int j = 0; j < 4; j++) {
            int col = n0 + tx * 4 + j;
            float pre = acc[i][j] + b1[col];
            p += fmaxf(pre, 0.f) * uu[col];
        }
#pragma unroll
        for (int m = 1; m < 16; m <<= 1) p += __shfl_xor(p, m);
        if (tx == 0) atomicAdd(&out[r0 + ty * 4 + i], p);
    }
}

// ---------------- launcher ----------------

extern "C" void kernel_launch(void* const* d_in, const int* in_sizes, int n_in,
                              void* d_out, int out_size, void* d_ws, size_t ws_size,
                              hipStream_t stream) {
    const float* smiles  = (const float*)d_in[0];
    const float* x       = (const float*)d_in[1];
    const int*   ei      = (const int*)d_in[2];
    const int*   batch   = (const int*)d_in[3];
    const float* emb_W1  = (const float*)d_in[4];
    const float* emb_b1  = (const float*)d_in[5];
    const float* emb_W2  = (const float*)d_in[6];
    const float* emb_b2  = (const float*)d_in[7];
    const float* conv1_W = (const float*)d_in[8];
    const float* conv1_b = (const float*)d_in[9];
    const float* conv2_W = (const float*)d_in[10];
    const float* conv2_b = (const float*)d_in[11];
    const float* gcn_fc_W = (const float*)d_in[12];
    const float* gcn_fc_b = (const float*)d_in[13];
    const float* fc1_W   = (const float*)d_in[14];
    const float* fc1_b   = (const float*)d_in[15];
    const float* fcf_W   = (const float*)d_in[16];
    const float* fcf_b   = (const float*)d_in[17];

    const int N = in_sizes[3];          // 131072
    const int E = in_sizes[2] / 2;      // 2097152
    const int B = in_sizes[0] / 768;    // 4096
    const int NB = N >> 8;              // 512 buckets of 256 nodes

    char* w = (char*)d_ws;
    int*   bhist  = (int*)w;                    w += 1024 * 4;         // zeroed
    float* cnt    = (float*)w;                  w += (size_t)B * 4;    // zeroed
    float* out_g  = (float*)w;                  w += (size_t)B * 4;    // zeroed
    int*   boff   = (int*)w;                    w += 512 * 4;
    int*   bcur   = (int*)w;                    w += 512 * 4;
    int*   degi   = (int*)w;                    w += (size_t)N * 4;
    float* dinv   = (float*)w;                  w += (size_t)N * 4;
    int*   off    = (int*)w;                    w += (size_t)N * 4;
    float* z      = (float*)w;                  w += (size_t)N * 4;
    float* vv     = (float*)w;                  w += 64 * 4;
    float* uu     = (float*)w;                  w += 1024 * 4;
    float* Cc     = (float*)w;                  w += 32 * 4;
    uint*  packed = (uint*)w;                   w += (size_t)E * 4;
    int*   csr_s  = (int*)w;                    w += (size_t)E * 4;
    uint*  ybf    = (uint*)w;                   /* N*32 uints (bf16x2) */

    const int* esrc = ei;
    const int* edst = ei + E;

    hipMemsetAsync(bhist, 0, (size_t)(1024 + 2 * B) * 4, stream);

    kb_hist<<<512, 256, NB * 4, stream>>>(edst, bhist, E, NB);
    kb_scan<<<1, 512, 0, stream>>>(bhist, boff, bcur);
    kb_part<<<(E + 255) / 256, 256, 0, stream>>>(esrc, edst, bcur, packed, E);
    k_gemm64_bf16<<<N / 64, 256, 0, stream>>>(x, conv1_W, ybf);
    kb_build<<<NB, 256, 0, stream>>>(packed, boff, bcur, degi, dinv, off, csr_s);
    k_cnt<<<(N + 255) / 256, 256, 0, stream>>>(batch, cnt, N);
    k_precompute<<<1, 256, 0, stream>>>(fc1_W, fc1_b, fcf_W, fcf_b, gcn_fc_W, gcn_fc_b,
                                        conv2_W, conv2_b, emb_W2, emb_b2, vv, uu, Cc);
    k_gather<<<N / 8, 256, 0, stream>>>(ybf, csr_s, off, degi, dinv,
                                        (const float2*)conv1_b, (const float2*)vv, z);
    k_pass2<<<N / 256, 256, 0, stream>>>(z, csr_s, off, degi, dinv, batch, out_g);
    k_ginit<<<(B + 255) / 256, 256, 0, stream>>>(out_g, cnt, Cc, (float*)d_out, B);
    k_embgemm<<<dim3(B / 64, 16), 256, 0, stream>>>(smiles, emb_W1, emb_b1, uu, (float*)d_out);
}

// Round 4
// 376.875 us; speedup vs baseline: 2.5865x; 2.5865x over previous
//
#include <hip/hip_runtime.h>

typedef unsigned int uint;

// ---------------- bf16 pack/unpack helpers ----------------

__device__ __forceinline__ uint pack_bf2(float a, float b) {
    uint ua = __float_as_uint(a), ub = __float_as_uint(b);
    ua = (ua + 0x7FFFu + ((ua >> 16) & 1u)) >> 16;        // RNE to bf16
    ub = (ub + 0x7FFFu + ((ub >> 16) & 1u)) >> 16;
    return ua | (ub << 16);
}
__device__ __forceinline__ float bf_lo(uint u) { return __uint_as_float(u << 16); }
__device__ __forceinline__ float bf_hi(uint u) { return __uint_as_float(u & 0xFFFF0000u); }

// ---------------- CSR build (bucketed, block-aggregated) ----------------

// 512-bucket histogram of dst>>8, LDS pre-aggregated; few global atomics
__global__ __launch_bounds__(256) void kb_hist(const int* __restrict__ dst,
                                               int* __restrict__ bhist, int E, int NB) {
    extern __shared__ int lh[];
    int tid = threadIdx.x;
    for (int i = tid; i < NB; i += 256) lh[i] = 0;
    __syncthreads();
    for (int e = blockIdx.x * 256 + tid; e < E; e += gridDim.x * 256)
        atomicAdd(&lh[dst[e] >> 8], 1);
    __syncthreads();
    for (int i = tid; i < NB; i += 256)
        if (lh[i]) atomicAdd(&bhist[i], lh[i]);
}

// exclusive scan of 512 bucket counts -> boff, bcur
__global__ void kb_scan(const int* __restrict__ bhist, int* __restrict__ boff,
                        int* __restrict__ bcur) {
    __shared__ int tmp[512];
    int tid = threadIdx.x;
    int v = bhist[tid];
    tmp[tid] = v;
    for (int d = 1; d < 512; d <<= 1) {
        __syncthreads();
        int t = (tid >= d) ? tmp[tid - d] : 0;
        __syncthreads();
        tmp[tid] += t;
    }
    int excl = tmp[tid] - v;
    boff[tid] = excl;
    bcur[tid] = excl;
}

// partition edges into buckets with per-block LDS aggregation:
// one reservation atomic per (block,bucket), then ranked scatter.
#define PART_CHUNK 8192
__global__ __launch_bounds__(256) void kb_part2(const int* __restrict__ src,
                                                const int* __restrict__ dst,
                                                int* __restrict__ bcur,
                                                uint* __restrict__ packed, int E) {
    __shared__ int lh[512];
    __shared__ int lbase[512];
    int tid = threadIdx.x;
    int e0 = blockIdx.x * PART_CHUNK;
    int e1 = min(e0 + PART_CHUNK, E);
    for (int i = tid; i < 512; i += 256) lh[i] = 0;
    __syncthreads();
    for (int e = e0 + tid; e < e1; e += 256)
        atomicAdd(&lh[dst[e] >> 8], 1);
    __syncthreads();
    for (int i = tid; i < 512; i += 256) {
        int c = lh[i];
        lbase[i] = c ? atomicAdd(&bcur[i], c) : 0;
        lh[i] = 0;
    }
    __syncthreads();
    for (int e = e0 + tid; e < e1; e += 256) {
        int s = src[e], d = dst[e];
        int b = d >> 8;
        int r = atomicAdd(&lh[b], 1);
        packed[lbase[b] + r] = ((uint)s << 8) | (uint)(d & 255);
    }
}

// per-bucket: exact per-node degrees, offsets, dinv, and final CSR fill
__global__ __launch_bounds__(256) void kb_build(const uint* __restrict__ packed,
                                                const int* __restrict__ boff,
                                                const int* __restrict__ bcur,
                                                int* __restrict__ degi,
                                                float* __restrict__ dinv,
                                                int* __restrict__ off,
                                                int* __restrict__ csr_s) {
    __shared__ int lh[256];
    __shared__ int lscan[256];
    __shared__ int lcur[256];
    int tid = threadIdx.x;
    int b = blockIdx.x;
    int base = boff[b];
    int cntE = bcur[b] - base;

    lh[tid] = 0;
    __syncthreads();
    for (int i = tid; i < cntE; i += 256)
        atomicAdd(&lh[packed[base + i] & 255u], 1);
    __syncthreads();
    int dg = lh[tid];
    lscan[tid] = dg;
    for (int d = 1; d < 256; d <<= 1) {
        __syncthreads();
        int t = (tid >= d) ? lscan[tid - d] : 0;
        __syncthreads();
        lscan[tid] += t;
    }
    int excl = lscan[tid] - dg;
    int node = (b << 8) + tid;
    degi[node] = dg;
    dinv[node] = rsqrtf((float)dg + 1.0f);
    off[node] = base + excl;
    lcur[tid] = excl;
    __syncthreads();
    for (int i = tid; i < cntE; i += 256) {
        uint u = packed[base + i];
        int d = (int)(u & 255u);
        int r = atomicAdd(&lcur[d], 1);
        csr_s[base + r] = (int)(u >> 8);
    }
}

// per-graph node counts
__global__ void k_cnt(const int* __restrict__ batch, float* __restrict__ cnt, int N) {
    int v = blockIdx.x * 256 + threadIdx.x;
    if (v < N) atomicAdd(&cnt[batch[v]], 1.0f);
}

// ---------------- y = x @ W1, output packed bf16 ----------------

__global__ __launch_bounds__(256) void k_gemm64_bf16(const float* __restrict__ A,
                                                     const float* __restrict__ W,
                                                     uint* __restrict__ ybf) {
    __shared__ float As[64][65];
    __shared__ float Ws[64][64];
    int tid = threadIdx.x;
    int r0 = blockIdx.x * 64;
    {
        int r = tid >> 2, cg = tid & 3;
        const float4* A4 = (const float4*)(A + (size_t)(r0 + r) * 64);
#pragma unroll
        for (int i = 0; i < 4; i++) {
            float4 a = A4[cg + 4 * i];
            int c = (cg + 4 * i) * 4;
            As[r][c + 0] = a.x; As[r][c + 1] = a.y; As[r][c + 2] = a.z; As[r][c + 3] = a.w;
        }
        const float4* W4 = (const float4*)W;
#pragma unroll
        for (int i = 0; i < 4; i++) {
            int idx = tid + 256 * i;
            float4 w = W4[idx];
            int k = idx >> 4, c = (idx & 15) * 4;
            *(float4*)&Ws[k][c] = w;
        }
    }
    __syncthreads();
    int ty = tid >> 4, tx = tid & 15;
    float acc[4][4] = {};
#pragma unroll 16
    for (int kk = 0; kk < 64; kk++) {
        float4 wv = *(const float4*)&Ws[kk][tx * 4];
        float a0 = As[ty * 4 + 0][kk];
        float a1 = As[ty * 4 + 1][kk];
        float a2 = As[ty * 4 + 2][kk];
        float a3 = As[ty * 4 + 3][kk];
        acc[0][0] += a0 * wv.x; acc[0][1] += a0 * wv.y; acc[0][2] += a0 * wv.z; acc[0][3] += a0 * wv.w;
        acc[1][0] += a1 * wv.x; acc[1][1] += a1 * wv.y; acc[1][2] += a1 * wv.z; acc[1][3] += a1 * wv.w;
        acc[2][0] += a2 * wv.x; acc[2][1] += a2 * wv.y; acc[2][2] += a2 * wv.z; acc[2][3] += a2 * wv.w;
        acc[3][0] += a3 * wv.x; acc[3][1] += a3 * wv.y; acc[3][2] += a3 * wv.z; acc[3][3] += a3 * wv.w;
    }
#pragma unroll
    for (int i = 0; i < 4; i++) {
        uint2 o;
        o.x = pack_bf2(acc[i][0], acc[i][1]);
        o.y = pack_bf2(acc[i][2], acc[i][3]);
        *(uint2*)&ybf[(size_t)(r0 + ty * 4 + i) * 32 + tx * 2] = o;
    }
}

// ---------------- pass 1: gather + relu-dot -> z ----------------

__global__ __launch_bounds__(256) void k_gather(const uint* __restrict__ ybf,
                                                const int* __restrict__ csr_s,
                                                const int* __restrict__ off,
                                                const int* __restrict__ degi,
                                                const float* __restrict__ dinv,
                                                const float2* __restrict__ b1_2,
                                                const float2* __restrict__ vv_2,
                                                float* __restrict__ z) {
    int tid = threadIdx.x;
    int lane = tid & 31;
    int v = blockIdx.x * 8 + (tid >> 5);
    float dv = dinv[v];
    int base = off[v], ce = degi[v];
    uint uy = ybf[(size_t)v * 32 + lane];
    float w0 = dv * dv;
    float ax = w0 * bf_lo(uy);
    float ay = w0 * bf_hi(uy);
    for (int j = 0; j < ce; j++) {
        int s = csr_s[base + j];
        float w = dv * dinv[s];
        uint u = ybf[(size_t)s * 32 + lane];
        ax += w * bf_lo(u);
        ay += w * bf_hi(u);
    }
    float2 b = b1_2[lane];
    float2 vv = vv_2[lane];
    float p = fmaxf(ax + b.x, 0.f) * vv.x + fmaxf(ay + b.y, 0.f) * vv.y;
#pragma unroll
    for (int m = 1; m < 32; m <<= 1) p += __shfl_xor(p, m);
    if (lane == 0) z[v] = p;
}

// ---------------- pass 2: aggregate z, pool into out_g ----------------

__global__ __launch_bounds__(256) void k_pass2(const float* __restrict__ z,
                                               const int* __restrict__ csr_s,
                                               const int* __restrict__ off,
                                               const int* __restrict__ degi,
                                               const float* __restrict__ dinv,
                                               const int* __restrict__ batch,
                                               float* __restrict__ out_g) {
    int v = blockIdx.x * 256 + threadIdx.x;
    float dv = dinv[v];
    int base = off[v], ce = degi[v];
    float acc = dv * dv * z[v];
    for (int j = 0; j < ce; j++) {
        int s = csr_s[base + j];
        acc += dv * dinv[s] * z[s];
    }
    atomicAdd(&out_g[batch[v]], acc);
}

// ---------------- fold trailing affine layers ----------------

__global__ void k_precompute(const float* __restrict__ fc1_W, const float* __restrict__ fc1_b,
                             const float* __restrict__ fcf_W, const float* __restrict__ fcf_b,
                             const float* __restrict__ gcn_fc_W, const float* __restrict__ gcn_fc_b,
                             const float* __restrict__ conv2_W, const float* __restrict__ conv2_b,
                             const float* __restrict__ emb_W2, const float* __restrict__ emb_b2,
                             float* __restrict__ vv, float* __restrict__ uu, float* __restrict__ Cc) {
    __shared__ float t1s[128], t2s[128];
    int tid = threadIdx.x;
    if (tid < 128) {
        float s = 0;
        for (int j = 0; j < 64; j++) s += fc1_W[tid * 64 + j] * fcf_W[j];
        t1s[tid] = s;
    }
    __syncthreads();
    if (tid < 128) {
        float s = 0;
        for (int m = 0; m < 64; m++) s += gcn_fc_W[tid * 64 + m] * t1s[64 + m];
        t2s[tid] = s;
    }
    __syncthreads();
    if (tid < 64) {
        float s = 0;
        for (int p = 0; p < 128; p++) s += conv2_W[tid * 128 + p] * t2s[p];
        vv[tid] = s;
    }
    for (int j = tid; j < 1024; j += 256) {
        float s = 0;
        for (int k = 0; k < 64; k++) s += emb_W2[j * 64 + k] * t1s[k];
        uu[j] = s;
    }
    if (tid == 0) {
        float c = fcf_b[0];
        for (int j = 0; j < 64; j++)  c += fc1_b[j] * fcf_W[j];
        for (int k = 0; k < 64; k++)  c += emb_b2[k] * t1s[k];
        for (int p = 0; p < 128; p++) c += conv2_b[p] * t2s[p];
        for (int m = 0; m < 64; m++)  c += gcn_fc_b[m] * t1s[64 + m];
        Cc[0] = c;
    }
}

__global__ void k_ginit(const float* __restrict__ out_g, const float* __restrict__ cnt,
                        const float* __restrict__ Cc, float* __restrict__ out, int B) {
    int b = blockIdx.x * 256 + threadIdx.x;
    if (b < B) {
        float c = cnt[b]; c = c < 1.f ? 1.f : c;
        out[b] = out_g[b] / c + Cc[0];
    }
}

// ---------------- embedding GEMM + relu-dot epilogue ----------------

__global__ __launch_bounds__(256) void k_embgemm(const float* __restrict__ A,
                                                 const float* __restrict__ Bm,
                                                 const float* __restrict__ b1,
                                                 const float* __restrict__ uu,
                                                 float* __restrict__ out) {
    __shared__ float As[16][68];
    __shared__ float Bs[16][64];
    int tid = threadIdx.x;
    int r0 = blockIdx.x * 64, n0 = blockIdx.y * 64;
    int ty = tid >> 4, tx = tid & 15;
    float acc[4][4] = {};

    for (int k0 = 0; k0 < 768; k0 += 16) {
        {
            int r = tid >> 2, kg = tid & 3;
            float4 a = *(const float4*)&A[(size_t)(r0 + r) * 768 + k0 + kg * 4];
            As[kg * 4 + 0][r] = a.x; As[kg * 4 + 1][r] = a.y;
            As[kg * 4 + 2][r] = a.z; As[kg * 4 + 3][r] = a.w;
            float4 b = *(const float4*)&Bm[(size_t)(k0 + (tid >> 4)) * 1024 + n0 + (tid & 15) * 4];
            *(float4*)&Bs[tid >> 4][(tid & 15) * 4] = b;
        }
        __syncthreads();
#pragma unroll
        for (int kk = 0; kk < 16; kk++) {
            float4 av = *(const float4*)&As[kk][ty * 4];
            float4 bv = *(const float4*)&Bs[kk][tx * 4];
            acc[0][0] += av.x * bv.x; acc[0][1] += av.x * bv.y; acc[0][2] += av.x * bv.z; acc[0][3] += av.x * bv.w;
            acc[1][0] += av.y * bv.x; acc[1][1] += av.y * bv.y; acc[1][2] += av.y * bv.z; acc[1][3] += av.y * bv.w;
            acc[2][0] += av.z * bv.x; acc[2][1] += av.z * bv.y; acc[2][2] += av.z * bv.z; acc[2][3] += av.z * bv.w;
            acc[3][0] += av.w * bv.x; acc[3][1] += av.w * bv.y; acc[3][2] += av.w * bv.z; acc[3][3] += av.w * bv.w;
        }
        __syncthreads();
    }

#pragma unroll
    for (int i = 0; i < 4; i++) {
        float p = 0;
#pragma unroll
        for (int j = 0; j < 4; j++) {
            int col = n0 + tx * 4 + j;
            float pre = acc[i][j] + b1[col];
            p += fmaxf(pre, 0.f) * uu[col];
        }
#pragma unroll
        for (int m = 1; m < 16; m <<= 1) p += __shfl_xor(p, m);
        if (tx == 0) atomicAdd(&out[r0 + ty * 4 + i], p);
    }
}

// ---------------- launcher ----------------

extern "C" void kernel_launch(void* const* d_in, const int* in_sizes, int n_in,
                              void* d_out, int out_size, void* d_ws, size_t ws_size,
                              hipStream_t stream) {
    const float* smiles  = (const float*)d_in[0];
    const float* x       = (const float*)d_in[1];
    const int*   ei      = (const int*)d_in[2];
    const int*   batch   = (const int*)d_in[3];
    const float* emb_W1  = (const float*)d_in[4];
    const float* emb_b1  = (const float*)d_in[5];
    const float* emb_W2  = (const float*)d_in[6];
    const float* emb_b2  = (const float*)d_in[7];
    const float* conv1_W = (const float*)d_in[8];
    const float* conv1_b = (const float*)d_in[9];
    const float* conv2_W = (const float*)d_in[10];
    const float* conv2_b = (const float*)d_in[11];
    const float* gcn_fc_W = (const float*)d_in[12];
    const float* gcn_fc_b = (const float*)d_in[13];
    const float* fc1_W   = (const float*)d_in[14];
    const float* fc1_b   = (const float*)d_in[15];
    const float* fcf_W   = (const float*)d_in[16];
    const float* fcf_b   = (const float*)d_in[17];

    const int N = in_sizes[3];          // 131072
    const int E = in_sizes[2] / 2;      // 2097152
    const int B = in_sizes[0] / 768;    // 4096
    const int NB = N >> 8;              // 512 buckets of 256 nodes

    char* w = (char*)d_ws;
    int*   bhist  = (int*)w;                    w += 1024 * 4;         // zeroed
    float* cnt    = (float*)w;                  w += (size_t)B * 4;    // zeroed
    float* out_g  = (float*)w;                  w += (size_t)B * 4;    // zeroed
    int*   boff   = (int*)w;                    w += 512 * 4;
    int*   bcur   = (int*)w;                    w += 512 * 4;
    int*   degi   = (int*)w;                    w += (size_t)N * 4;
    float* dinv   = (float*)w;                  w += (size_t)N * 4;
    int*   off    = (int*)w;                    w += (size_t)N * 4;
    float* z      = (float*)w;                  w += (size_t)N * 4;
    float* vv     = (float*)w;                  w += 64 * 4;
    float* uu     = (float*)w;                  w += 1024 * 4;
    float* Cc     = (float*)w;                  w += 32 * 4;
    uint*  packed = (uint*)w;                   w += (size_t)E * 4;
    int*   csr_s  = (int*)w;                    w += (size_t)E * 4;
    uint*  ybf    = (uint*)w;                   /* N*32 uints (bf16x2) */

    const int* esrc = ei;
    const int* edst = ei + E;

    hipMemsetAsync(bhist, 0, (size_t)(1024 + 2 * B) * 4, stream);

    kb_hist<<<128, 256, NB * 4, stream>>>(edst, bhist, E, NB);
    kb_scan<<<1, 512, 0, stream>>>(bhist, boff, bcur);
    kb_part2<<<(E + PART_CHUNK - 1) / PART_CHUNK, 256, 0, stream>>>(esrc, edst, bcur, packed, E);
    k_gemm64_bf16<<<N / 64, 256, 0, stream>>>(x, conv1_W, ybf);
    kb_build<<<NB, 256, 0, stream>>>(packed, boff, bcur, degi, dinv, off, csr_s);
    k_cnt<<<(N + 255) / 256, 256, 0, stream>>>(batch, cnt, N);
    k_precompute<<<1, 256, 0, stream>>>(fc1_W, fc1_b, fcf_W, fcf_b, gcn_fc_W, gcn_fc_b,
                                        conv2_W, conv2_b, emb_W2, emb_b2, vv, uu, Cc);
    k_gather<<<N / 8, 256, 0, stream>>>(ybf, csr_s, off, degi, dinv,
                                        (const float2*)conv1_b, (const float2*)vv, z);
    k_pass2<<<N / 256, 256, 0, stream>>>(z, csr_s, off, degi, dinv, batch, out_g);
    k_ginit<<<(B + 255) / 256, 256, 0, stream>>>(out_g, cnt, Cc, (float*)d_out, B);
    k_embgemm<<<dim3(B / 64, 16), 256, 0, stream>>>(smiles, emb_W1, emb_b1, uu, (float*)d_out);
}